// Round 18
// baseline (30.284 us; speedup 1.0000x reference)
//
#include <hip/hip_runtime.h>
#include <math.h>

typedef float f32x2 __attribute__((ext_vector_type(2)));

#define A_HEADS 8
#define BB 32
#define HH 160
#define WW 160

// Two horizontally-adjacent pixels per thread (w0, w0+1). The per-wave scalar
// weight stream (648 floats via s_load) now feeds 128 pixels instead of 64;
// patches share 6/9 taps; output is one aligned float2 store.
// block(16,16), grid(5, 320) -> 1600 blocks, 6400 waves (~25/CU).
__global__ __launch_bounds__(256) void vi_kernel(
    const float* __restrict__ values,
    const float* __restrict__ rewards,
    const float* __restrict__ weight,
    float* __restrict__ out)
{
    int tx = threadIdx.x;                         // 0..15
    int ty = threadIdx.y;                         // 0..15
    int w0 = (blockIdx.x * 16 + tx) * 2;          // even col; covers w0, w0+1
    int hb = blockIdx.y * 16 + ty;                // 0..B*H-1
    int h  = hb % HH;
    int b  = hb / HH;

    const float* vbase = values  + b * (HH * WW);
    const float* rbase = rewards + b * (HH * WW);

    // rv rows h-1..h+1, cols w0-1..w0+2 (zero-padded) -> rc[3][4]
    float rc[3][4];
    #pragma unroll
    for (int rr = 0; rr < 3; ++rr) {
        int hh = h + rr - 1;
        bool hok = (hh >= 0) && (hh < HH);
        #pragma unroll
        for (int c = 0; c < 4; ++c) {
            int ww = w0 + c - 1;
            bool ok = hok && (ww >= 0) && (ww < WW);
            float v = 0.0f;
            if (ok) {
                int off = hh * WW + ww;
                v = vbase[off] + rbase[off];
            }
            rc[rr][c] = v;
        }
    }

    // per-pixel patches: pixel p uses cols p..p+2 of rc
    float patch0[9], patch1[9];
    #pragma unroll
    for (int rr = 0; rr < 3; ++rr) {
        #pragma unroll
        for (int c = 0; c < 3; ++c) {
            patch0[rr * 3 + c] = rc[rr][c];
            patch1[rr * 3 + c] = rc[rr][c + 1];
        }
    }

    // tap pairs (j, j+1) for packed FMA, per pixel
    f32x2 pp0[4], pp1[4];
    #pragma unroll
    for (int j2 = 0; j2 < 4; ++j2) {
        pp0[j2] = (f32x2){patch0[2 * j2], patch0[2 * j2 + 1]};
        pp1[j2] = (f32x2){patch1[2 * j2], patch1[2 * j2 + 1]};
    }

    float best0 = -INFINITY, best1 = -INFINITY;
    #pragma unroll
    for (int a = 0; a < A_HEADS; ++a) {
        float den0 = 0.0f, num0 = 0.0f;
        float den1 = 0.0f, num1 = 0.0f;
        #pragma unroll
        for (int i = 0; i < 9; ++i) {
            const float* wr = weight + (a * 9 + i) * 9;   // uniform row base
            f32x2 acc0 = (f32x2){0.0f, 0.0f};
            f32x2 acc1 = (f32x2){0.0f, 0.0f};
            #pragma unroll
            for (int j2 = 0; j2 < 4; ++j2) {
                // one SGPR weight pair feeds both pixels' v_pk_fma_f32
                f32x2 wp = (f32x2){wr[2 * j2], wr[2 * j2 + 1]};
                acc0 = __builtin_elementwise_fma(pp0[j2], wp, acc0);
                acc1 = __builtin_elementwise_fma(pp1[j2], wp, acc1);
            }
            float l0 = acc0.x + acc0.y;  l0 = fmaf(patch0[8], wr[8], l0);
            float l1 = acc1.x + acc1.y;  l1 = fmaf(patch1[8], wr[8], l1);
            // softmax without max-subtraction (shift-invariant, logits O(few))
            float e0 = __expf(l0);
            float e1 = __expf(l1);
            den0 += e0;  num0 = fmaf(patch0[i], e0, num0);
            den1 += e1;  num1 = fmaf(patch1[i], e1, num1);
        }
        best0 = fmaxf(best0, num0 * __builtin_amdgcn_rcpf(den0));
        best1 = fmaxf(best1, num1 * __builtin_amdgcn_rcpf(den1));
    }

    // adjacent outputs, 8B-aligned (w0 even) -> single float2 store
    f32x2 res = (f32x2){best0, best1};
    *reinterpret_cast<f32x2*>(out + hb * WW + w0) = res;
}

extern "C" void kernel_launch(void* const* d_in, const int* in_sizes, int n_in,
                              void* d_out, int out_size, void* d_ws, size_t ws_size,
                              hipStream_t stream)
{
    const float* values  = (const float*)d_in[0];
    const float* rewards = (const float*)d_in[1];
    const float* weight  = (const float*)d_in[2];
    float* out = (float*)d_out;

    dim3 block(16, 16);
    dim3 grid(WW / 32, (BB * HH) / 16);   // (5, 320) -> 1600 blocks, 6400 waves
    vi_kernel<<<grid, block, 0, stream>>>(values, rewards, weight, out);
}

// Round 19
// 26.083 us; speedup vs baseline: 1.1611x; 1.1611x over previous
//
#include <hip/hip_runtime.h>
#include <math.h>

typedef float f32x2 __attribute__((ext_vector_type(2)));

#define A_HEADS 8
#define BB 32
#define HH 160
#define WW 160

// One thread per output pixel, 12800 waves. Weights read directly (uniform,
// constant-index -> scalar pipe). Conv packed along taps j: per logit
// 4 x v_pk_fma_f32 + horizontal add + tail fma.
// __launch_bounds__(256, 8): force 8 waves/SIMD (VGPR budget 64) — testing
// the occupancy-cliff hypothesis (waves/SIMD halve at VGPR>64).
__global__ __launch_bounds__(256, 8) void vi_kernel(
    const float* __restrict__ values,
    const float* __restrict__ rewards,
    const float* __restrict__ weight,
    float* __restrict__ out)
{
    int w  = blockIdx.x * 32 + threadIdx.x;   // 0..159 (grid.x = 5)
    int hb = blockIdx.y * 8 + threadIdx.y;    // 0..B*H-1
    int h  = hb % HH;
    int b  = hb / HH;

    const float* vbase = values  + b * (HH * WW);
    const float* rbase = rewards + b * (HH * WW);

    // 3x3 zero-padded patch of rv = values + rewards around (h, w)
    float patch[9];
    #pragma unroll
    for (int di = 0; di < 3; ++di) {
        int hh = h + di - 1;
        bool hok = (hh >= 0) && (hh < HH);
        #pragma unroll
        for (int dj = 0; dj < 3; ++dj) {
            int ww = w + dj - 1;
            bool ok = hok && (ww >= 0) && (ww < WW);
            float val = 0.0f;
            if (ok) {
                int off = hh * WW + ww;
                val = vbase[off] + rbase[off];
            }
            patch[di * 3 + dj] = val;
        }
    }

    // patch pairs (j, j+1), built once, reused by all 72 logits
    f32x2 patchp[4];
    #pragma unroll
    for (int j2 = 0; j2 < 4; ++j2)
        patchp[j2] = (f32x2){patch[2 * j2], patch[2 * j2 + 1]};

    float best = -INFINITY;
    #pragma unroll
    for (int a = 0; a < A_HEADS; ++a) {
        float den = 0.0f;
        float num = 0.0f;
        #pragma unroll
        for (int i = 0; i < 9; ++i) {
            const float* wr = weight + (a * 9 + i) * 9;   // uniform row base
            f32x2 acc2 = (f32x2){0.0f, 0.0f};
            #pragma unroll
            for (int j2 = 0; j2 < 4; ++j2) {
                // adjacent uniform pair -> SGPR pair operand for v_pk_fma_f32
                f32x2 wpair = (f32x2){wr[2 * j2], wr[2 * j2 + 1]};
                acc2 = __builtin_elementwise_fma(patchp[j2], wpair, acc2);
            }
            float logit = acc2.x + acc2.y;
            logit = fmaf(patch[8], wr[8], logit);
            // softmax without max-subtraction (shift-invariant, logits O(few))
            float e = __expf(logit);
            den += e;
            num = fmaf(patch[i], e, num);
        }
        best = fmaxf(best, num * __builtin_amdgcn_rcpf(den));
    }

    out[hb * WW + w] = best;
}

extern "C" void kernel_launch(void* const* d_in, const int* in_sizes, int n_in,
                              void* d_out, int out_size, void* d_ws, size_t ws_size,
                              hipStream_t stream)
{
    const float* values  = (const float*)d_in[0];
    const float* rewards = (const float*)d_in[1];
    const float* weight  = (const float*)d_in[2];
    float* out = (float*)d_out;

    dim3 block(32, 8);
    dim3 grid(WW / 32, (BB * HH) / 8);   // (5, 640) -> 3200 blocks, 12800 waves
    vi_kernel<<<grid, block, 0, stream>>>(values, rewards, weight, out);
}